// Round 3
// baseline (1034.931 us; speedup 1.0000x reference)
//
#include <hip/hip_runtime.h>
#include <cstdint>

#define BH    64
#define NSEQ  4096
#define DH    64
#define MF    256
#define EPS   1e-6f

typedef float f32;
typedef __attribute__((ext_vector_type(4))) float f32x4;

// ws layout: [ctx: 64*256*64 f32][ksum: 64*256 f32]
#define CTX_FLOATS (BH * MF * 64)
#define WS_FLOATS  (CTX_FLOATS + BH * MF)

// gelu(s) = 0.5*s*(1+erf(s/sqrt2)) + EPS, erf via A&S 7.1.26 (|err|<=1.5e-7)
__device__ __forceinline__ float gelu_eps(float s) {
    float x  = s * 0.70710678118654752f;
    float ax = fabsf(x);
    float t  = __builtin_amdgcn_rcpf(fmaf(0.3275911f, ax, 1.0f));
    float p  = t * fmaf(t, fmaf(t, fmaf(t, fmaf(t, 1.061405429f, -1.453152027f),
                                        1.421413741f), -0.284496736f), 0.254829592f);
    float e  = __expf(-(ax * ax));
    float er = copysignf(fmaf(-p, e, 1.0f), x);
    return fmaf(0.5f * s, er, fmaf(0.5f, s, EPS));
}

__global__ void zero_ws_kernel(f32x4* __restrict__ p) {
    p[blockIdx.x * 256 + threadIdx.x] = (f32x4){0.f, 0.f, 0.f, 0.f};
}

// stage P^T chunk (64 feats x 64 d) transposed+swizzled into sP4[d][fq^(d&15)]
__device__ __forceinline__ void stage_P(const f32* __restrict__ Pg_, int f, f32x4* sP4) {
    const f32x4* Pg = (const f32x4*)(Pg_ + (size_t)f * 64 * DH);
    f32* base = (f32*)sP4;
    #pragma unroll
    for (int p = 0; p < 2; ++p) {
        int m2 = threadIdx.x + p * 512;          // 0..1023
        int feat = m2 >> 4, dq = m2 & 15;
        f32x4 val = Pg[m2];
        #pragma unroll
        for (int jj = 0; jj < 4; ++jj) {
            int d = dq * 4 + jj;
            base[d * 64 + (((feat >> 2) ^ (d & 15)) << 2) + (feat & 3)] = val[jj];
        }
    }
}

// ---------------------------------------------------------------------------
// kside: grid 64bh x 4f x 4rg.  Block: f-chunk fixed, 1024 rows (8 tiles x 128).
//   kp = gelu(K@P^T)+eps ; ctx[f64][e64] += kp^T@V ; ksum[f64] += colsum(kp)
// ---------------------------------------------------------------------------
__global__ __launch_bounds__(512, 4) void kside_kernel(
    const f32* __restrict__ Kg_, const f32* __restrict__ Vg_,
    const f32* __restrict__ Pg_, f32* __restrict__ ctx_ws,
    f32* __restrict__ ksum_ws)
{
    __shared__ f32x4 sP4[64 * 16];    // 16 KB
    __shared__ f32x4 kp4[128 * 16];   // 32 KB, [row][fq ^ (row&15)]

    const int tid = threadIdx.x;
    const int bh  = blockIdx.x >> 4;
    const int f   = (blockIdx.x >> 2) & 3;
    const int rg  = blockIdx.x & 3;
    const size_t rowbase0 = (size_t)bh * NSEQ + rg * 1024;

    const int srg = tid >> 4, sfg = tid & 15;        // S-GEMM: 4 rows x 4 feats
    const int h   = tid >> 8;                        // ctx-GEMM row-half
    const int t8  = tid & 255;
    const int cfq = t8 & 15, ceg = t8 >> 4;          // ctx: 4 feats x 4 e

    stage_P(Pg_, f, sP4);
    __syncthreads();

    f32x4 ctxacc[4];
    f32x4 ksacc = (f32x4){0.f, 0.f, 0.f, 0.f};
    #pragma unroll
    for (int fi = 0; fi < 4; ++fi) ctxacc[fi] = (f32x4){0.f, 0.f, 0.f, 0.f};

    for (int t = 0; t < 8; ++t) {
        const f32* Kg = Kg_ + (rowbase0 + t * 128) * DH;

        // S = Ktile @ P^T (128r x 64f, K-dim 64)
        f32x4 s[4];
        #pragma unroll
        for (int r = 0; r < 4; ++r) s[r] = (f32x4){0.f, 0.f, 0.f, 0.f};
        #pragma unroll 4
        for (int kb = 0; kb < 16; ++kb) {
            f32x4 a[4];
            #pragma unroll
            for (int r = 0; r < 4; ++r)
                a[r] = *(const f32x4*)(Kg + (size_t)(srg * 4 + r) * DH + kb * 4);
            #pragma unroll
            for (int kk = 0; kk < 4; ++kk) {
                int d = kb * 4 + kk;
                f32x4 b = sP4[d * 16 + (sfg ^ (d & 15))];
                #pragma unroll
                for (int r = 0; r < 4; ++r) s[r] += a[r][kk] * b;
            }
        }
        // gelu + swizzled kp store (prev ctx-GEMM readers done at loop-end barrier)
        #pragma unroll
        for (int r = 0; r < 4; ++r) {
            int row = srg * 4 + r;
            f32x4 g;
            #pragma unroll
            for (int i = 0; i < 4; ++i) g[i] = gelu_eps(s[r][i]);
            kp4[row * 16 + (sfg ^ (row & 15))] = g;
        }
        __syncthreads();

        // ctx += kp^T @ V over this tile; halves split rows
        const f32* Vg = Vg_ + (rowbase0 + t * 128 + h * 64) * DH;
        #pragma unroll 2
        for (int rb = 0; rb < 16; ++rb) {
            f32x4 a4[4], b4[4];
            #pragma unroll
            for (int rr = 0; rr < 4; ++rr) {
                int row = h * 64 + rb * 4 + rr;
                a4[rr] = kp4[row * 16 + (cfq ^ (row & 15))];
                b4[rr] = *(const f32x4*)(Vg + (size_t)(rb * 4 + rr) * DH + ceg * 4);
            }
            #pragma unroll
            for (int rr = 0; rr < 4; ++rr)
                #pragma unroll
                for (int fi = 0; fi < 4; ++fi)
                    ctxacc[fi] += a4[rr][fi] * b4[rr];
            if (ceg == 0) {
                #pragma unroll
                for (int rr = 0; rr < 4; ++rr) ksacc += a4[rr];
            }
        }
        __syncthreads();   // protect kp overwrite next tile
    }

    f32* cb = ctx_ws + ((size_t)bh * MF + f * 64 + cfq * 4) * 64 + ceg * 4;
    #pragma unroll
    for (int fi = 0; fi < 4; ++fi)
        #pragma unroll
        for (int ei = 0; ei < 4; ++ei)
            atomicAdd(cb + (size_t)fi * 64 + ei, ctxacc[fi][ei]);
    if (ceg == 0) {
        f32* kb_ = ksum_ws + (size_t)bh * MF + f * 64 + cfq * 4;
        #pragma unroll
        for (int fi = 0; fi < 4; ++fi) atomicAdd(kb_ + fi, ksacc[fi]);
    }
}

// ---------------------------------------------------------------------------
// qside: grid 64bh x 32chunks, 128 rows each.
//   qp = gelu(Q@P^T)+eps ; num = qp@ctx ; den = qp.ksum ; out = num/den
// ---------------------------------------------------------------------------
__global__ __launch_bounds__(512, 4) void qside_kernel(
    const f32* __restrict__ Qg_, const f32* __restrict__ Pg_,
    const f32* __restrict__ ctx_ws, const f32* __restrict__ ksum_ws,
    f32* __restrict__ out)
{
    __shared__ f32x4 qp4[128 * 16];   // 32 KB
    __shared__ f32x4 sP4[64 * 16];    // 16 KB
    __shared__ f32x4 sks[64];         // 1 KB

    const int tid = threadIdx.x;
    const int bh  = blockIdx.x >> 5;
    const int ch  = blockIdx.x & 31;
    const size_t rowbase = (size_t)bh * NSEQ + ch * 128;

    const int srg = tid >> 4, sfg = tid & 15;   // S-GEMM: 4 rows x 4 feats
    const int org = tid >> 4, oeg = tid & 15;   // num:    4 rows x 4 e

    if (tid < 64) sks[tid] = ((const f32x4*)(ksum_ws + (size_t)bh * MF))[tid];

    const f32* Qg = Qg_ + rowbase * DH;

    f32x4 num[4];
    float den[4] = {0.f, 0.f, 0.f, 0.f};
    #pragma unroll
    for (int r = 0; r < 4; ++r) num[r] = (f32x4){0.f, 0.f, 0.f, 0.f};

    for (int f = 0; f < 4; ++f) {
        stage_P(Pg_, f, sP4);            // safe: prior S-GEMM sP reads ended before
        __syncthreads();                 // prev barrier; covers sks on f=0 too

        f32x4 s[4];
        #pragma unroll
        for (int r = 0; r < 4; ++r) s[r] = (f32x4){0.f, 0.f, 0.f, 0.f};
        #pragma unroll 4
        for (int kb = 0; kb < 16; ++kb) {
            f32x4 a[4];
            #pragma unroll
            for (int r = 0; r < 4; ++r)
                a[r] = *(const f32x4*)(Qg + (size_t)(srg * 4 + r) * DH + kb * 4);
            #pragma unroll
            for (int kk = 0; kk < 4; ++kk) {
                int d = kb * 4 + kk;
                f32x4 b = sP4[d * 16 + (sfg ^ (d & 15))];
                #pragma unroll
                for (int r = 0; r < 4; ++r) s[r] += a[r][kk] * b;
            }
        }
        #pragma unroll
        for (int r = 0; r < 4; ++r) {
            int row = srg * 4 + r;
            f32x4 g;
            #pragma unroll
            for (int i = 0; i < 4; ++i) g[i] = gelu_eps(s[r][i]);
            qp4[row * 16 + (sfg ^ (row & 15))] = g;
        }
        __syncthreads();

        // num += qp_f @ ctx_f ; den += qp_f . ksum_f   (ctx from global via L1)
        const f32* Cg = ctx_ws + ((size_t)bh * MF + f * 64) * 64;
        #pragma unroll 2
        for (int kb = 0; kb < 16; ++kb) {
            f32x4 a[4];
            #pragma unroll
            for (int r = 0; r < 4; ++r) {
                int row = org * 4 + r;
                a[r] = qp4[row * 16 + (kb ^ (row & 15))];
            }
            f32x4 ks = sks[f * 16 + kb];
            #pragma unroll
            for (int kk = 0; kk < 4; ++kk) {
                f32x4 b = *(const f32x4*)(Cg + (size_t)(kb * 4 + kk) * 64 + oeg * 4);
                #pragma unroll
                for (int r = 0; r < 4; ++r) num[r] += a[r][kk] * b;
            }
            #pragma unroll
            for (int r = 0; r < 4; ++r)
                den[r] += a[r][0] * ks[0] + a[r][1] * ks[1] + a[r][2] * ks[2] + a[r][3] * ks[3];
        }
    }

    #pragma unroll
    for (int r = 0; r < 4; ++r) {
        int row = org * 4 + r;
        float dinv = 1.0f / den[r];
        *(f32x4*)(out + (rowbase + row) * DH + oeg * 4) = num[r] * dinv;
    }
}

extern "C" void kernel_launch(void* const* d_in, const int* in_sizes, int n_in,
                              void* d_out, int out_size, void* d_ws, size_t ws_size,
                              hipStream_t stream) {
    const f32* q    = (const f32*)d_in[0];
    const f32* k    = (const f32*)d_in[1];
    const f32* v    = (const f32*)d_in[2];
    const f32* proj = (const f32*)d_in[3];
    f32* out     = (f32*)d_out;
    f32* ctx_ws  = (f32*)d_ws;
    f32* ksum_ws = ctx_ws + CTX_FLOATS;

    const int nzero = WS_FLOATS / 4;   // 1,052,672 quads = 4112 * 256
    hipLaunchKernelGGL(zero_ws_kernel, dim3(nzero / 256), dim3(256), 0, stream,
                       (f32x4*)d_ws);
    hipLaunchKernelGGL(kside_kernel, dim3(BH * 16), dim3(512), 0, stream,
                       k, v, proj, ctx_ws, ksum_ws);
    hipLaunchKernelGGL(qside_kernel, dim3(BH * 32), dim3(512), 0, stream,
                       q, proj, ctx_ws, ksum_ws, out);
}

// Round 4
// 924.502 us; speedup vs baseline: 1.1194x; 1.1194x over previous
//
#include <hip/hip_runtime.h>
#include <cstdint>

#define BH    64
#define NSEQ  4096
#define DH    64
#define MF    256
#define EPS   1e-6f

typedef float f32;
typedef __attribute__((ext_vector_type(4))) float f32x4;

// ws layout: [ctx: 64*256*64 f32][ksum: 64*256 f32]
#define CTX_FLOATS (BH * MF * 64)
#define WS_FLOATS  (CTX_FLOATS + BH * MF)   // 1,064,960 floats = 266,240 quads
#define ZV ((f32x4){0.f, 0.f, 0.f, 0.f})
#define SW(q, r) ((q) ^ ((r) & 15))

// gelu(s) = 0.5*s*(1+erf(s/sqrt2)) + EPS, erf via A&S 7.1.26 (|err|<=1.5e-7)
__device__ __forceinline__ float gelu_eps(float s) {
    float x  = s * 0.70710678118654752f;
    float ax = fabsf(x);
    float t  = __builtin_amdgcn_rcpf(fmaf(0.3275911f, ax, 1.0f));
    float p  = t * fmaf(t, fmaf(t, fmaf(t, fmaf(t, 1.061405429f, -1.453152027f),
                                        1.421413741f), -0.284496736f), 0.254829592f);
    float e  = __expf(-(ax * ax));
    float er = copysignf(fmaf(-p, e, 1.0f), x);
    return fmaf(0.5f * s, er, fmaf(0.5f, s, EPS));
}

__global__ void zero_ws_kernel(f32x4* __restrict__ p) {
    p[blockIdx.x * 256 + threadIdx.x] = ZV;
}

// stage P^T chunk f (64 feats x 64 d) transposed+swizzled: sP[d][fq ^ (d&15)]
__device__ __forceinline__ void stage_P(const f32* __restrict__ Pg_, int f,
                                        f32x4* sP, int tid) {
    const f32x4* Pg = (const f32x4*)(Pg_ + (size_t)f * 64 * DH);
    f32* base = (f32*)sP;
    #pragma unroll
    for (int p = 0; p < 4; ++p) {
        int m2 = tid + p * 256;          // 0..1023
        int feat = m2 >> 4, dq = m2 & 15;
        f32x4 val = Pg[m2];
        #pragma unroll
        for (int jj = 0; jj < 4; ++jj) {
            int d = dq * 4 + jj;
            base[d * 64 + (SW(feat >> 2, d) << 2) + (feat & 3)] = val[jj];
        }
    }
}

// ---------------------------------------------------------------------------
// kside: grid 64bh x 2rg x 4f (f minor => V L2 reuse). Block: 2048 rows,
// 16 tiles x 128. kp = gelu(K@P^T)+eps ; ctx += kp^T@V ; ksum += colsum(kp)
// ---------------------------------------------------------------------------
__global__ __launch_bounds__(256, 2) void kside_kernel(
    const f32* __restrict__ Kg_, const f32* __restrict__ Vg_,
    const f32* __restrict__ Pg_, f32* __restrict__ ctx_ws,
    f32* __restrict__ ksum_ws)
{
    __shared__ f32x4 sP[64 * 16];    // 16 KB
    __shared__ f32x4 kp[128 * 16];   // 32 KB, [row][q ^ (row&15)]

    const int tid = threadIdx.x;
    const int b   = blockIdx.x;
    const int f   = b & 3;
    const int rg2 = (b >> 2) & 1;
    const int bh  = b >> 3;
    const size_t rowbase = (size_t)bh * NSEQ + rg2 * 2048;

    const int srg = tid >> 4, sfg = tid & 15;              // S: 8 rows x 1 fq
    const int g = tid >> 6, t6 = tid & 63;
    const int cfg = t6 >> 3, ceg = t6 & 7;                 // ctx: 8f x 8e, K=32

    stage_P(Pg_, f, sP, tid);
    __syncthreads();

    f32x4 ctxacc[8][2];
    f32x4 ksp = ZV;
    #pragma unroll
    for (int fi = 0; fi < 8; ++fi) { ctxacc[fi][0] = ZV; ctxacc[fi][1] = ZV; }

    for (int t = 0; t < 16; ++t) {
        const f32* Kg = Kg_ + (rowbase + t * 128) * DH;

        // S-GEMM: 8 rows x 4 feats, K=64
        f32x4 s[8];
        #pragma unroll
        for (int j = 0; j < 8; ++j) s[j] = ZV;
        #pragma unroll 4
        for (int kb = 0; kb < 16; ++kb) {
            f32x4 a[8];
            #pragma unroll
            for (int j = 0; j < 8; ++j)
                a[j] = *(const f32x4*)(Kg + (size_t)(srg * 8 + j) * DH + kb * 4);
            #pragma unroll
            for (int kk = 0; kk < 4; ++kk) {
                int d = kb * 4 + kk;
                f32x4 bq = sP[d * 16 + SW(sfg, d)];
                #pragma unroll
                for (int j = 0; j < 8; ++j) s[j] += a[j][kk] * bq;
            }
        }
        f32x4 gq[8];
        #pragma unroll
        for (int j = 0; j < 8; ++j) {
            #pragma unroll
            for (int i = 0; i < 4; ++i) gq[j][i] = gelu_eps(s[j][i]);
            ksp += gq[j];
        }
        __syncthreads();   // prev-tile ctx-GEMM kp reads done
        #pragma unroll
        for (int j = 0; j < 8; ++j) {
            int row = srg * 8 + j;
            kp[row * 16 + SW(sfg, row)] = gq[j];
        }
        __syncthreads();   // kp ready

        // ctx-GEMM: group g covers rows g*32..+31; thread 8f x 8e
        const f32* Vg = Vg_ + (rowbase + t * 128 + g * 32) * DH;
        #pragma unroll 4
        for (int k = 0; k < 32; ++k) {
            int row = g * 32 + k;
            f32x4 a0 = kp[row * 16 + SW(2 * cfg,     row)];
            f32x4 a1 = kp[row * 16 + SW(2 * cfg + 1, row)];
            f32x4 b0 = *(const f32x4*)(Vg + (size_t)k * DH + ceg * 8);
            f32x4 b1 = *(const f32x4*)(Vg + (size_t)k * DH + ceg * 8 + 4);
            #pragma unroll
            for (int fi = 0; fi < 4; ++fi) {
                ctxacc[fi][0]     += a0[fi] * b0;
                ctxacc[fi][1]     += a0[fi] * b1;
                ctxacc[4 + fi][0] += a1[fi] * b0;
                ctxacc[4 + fi][1] += a1[fi] * b1;
            }
        }
    }

    // ksum: reduce 16 srg-partials via kp scratch (kp dead after barrier)
    __syncthreads();
    ((f32x4*)kp)[sfg * 16 + srg] = ksp;
    __syncthreads();
    if (tid < 16) {
        f32x4 sum = ZV;
        #pragma unroll
        for (int r = 0; r < 16; ++r) sum += ((f32x4*)kp)[tid * 16 + r];
        f32* kb_ = ksum_ws + (size_t)bh * MF + f * 64 + tid * 4;
        #pragma unroll
        for (int i = 0; i < 4; ++i) atomicAdd(kb_ + i, sum[i]);
    }

    f32* cb = ctx_ws + ((size_t)bh * MF + f * 64 + cfg * 8) * 64 + ceg * 8;
    #pragma unroll
    for (int fi = 0; fi < 8; ++fi)
        #pragma unroll
        for (int h = 0; h < 2; ++h)
            #pragma unroll
            for (int ei = 0; ei < 4; ++ei)
                atomicAdd(cb + (size_t)fi * 64 + h * 4 + ei, ctxacc[fi][h][ei]);
}

// ---------------------------------------------------------------------------
// qside: grid 64bh x 32ch, 128 rows. qp = gelu(Q@P^T)+eps ;
// num = qp@ctx ; den = qp.ksum ; out = num/den. sP/sctx share sU (16 KB).
// ---------------------------------------------------------------------------
__global__ __launch_bounds__(256, 2) void qside_kernel(
    const f32* __restrict__ Qg_, const f32* __restrict__ Pg_,
    const f32* __restrict__ ctx_ws, const f32* __restrict__ ksum_ws,
    f32* __restrict__ out)
{
    __shared__ f32x4 qp[128 * 16];   // 32 KB
    __shared__ f32x4 sU[64 * 16];    // 16 KB: P^T then ctx chunk
    __shared__ f32x4 sks[64];        // 1 KB

    const int tid = threadIdx.x;
    const int bh  = blockIdx.x >> 5;
    const int ch  = blockIdx.x & 31;
    const size_t rowbase = (size_t)bh * NSEQ + ch * 128;

    const int rg = tid >> 4, cg = tid & 15;   // S: 8r x 1 fq ; num: 8r x 1 eq

    if (tid < 64) sks[tid] = ((const f32x4*)(ksum_ws + (size_t)bh * MF))[tid];

    const f32* Qg = Qg_ + rowbase * DH;

    f32x4 num[8];
    float den[8];
    #pragma unroll
    for (int j = 0; j < 8; ++j) { num[j] = ZV; den[j] = 0.f; }

    for (int f = 0; f < 4; ++f) {
        stage_P(Pg_, f, sU, tid);
        __syncthreads();   // B1: sP ready (f=0 also covers sks)

        // S-GEMM: 8 rows x 4 feats, K=64
        f32x4 s[8];
        #pragma unroll
        for (int j = 0; j < 8; ++j) s[j] = ZV;
        #pragma unroll 4
        for (int kb = 0; kb < 16; ++kb) {
            f32x4 a[8];
            #pragma unroll
            for (int j = 0; j < 8; ++j)
                a[j] = *(const f32x4*)(Qg + (size_t)(rg * 8 + j) * DH + kb * 4);
            #pragma unroll
            for (int kk = 0; kk < 4; ++kk) {
                int d = kb * 4 + kk;
                f32x4 bq = sU[d * 16 + SW(cg, d)];
                #pragma unroll
                for (int j = 0; j < 8; ++j) s[j] += a[j][kk] * bq;
            }
        }
        #pragma unroll
        for (int j = 0; j < 8; ++j) {
            int row = rg * 8 + j;
            f32x4 gq;
            #pragma unroll
            for (int i = 0; i < 4; ++i) gq[i] = gelu_eps(s[j][i]);
            qp[row * 16 + SW(cg, row)] = gq;
        }
        __syncthreads();   // B2: qp ready AND sU (P) reads done

        {   // stage ctx chunk into sU, swizzled [k][eq ^ (k&15)]
            const f32x4* Cg = (const f32x4*)(ctx_ws + ((size_t)bh * MF + f * 64) * 64);
            #pragma unroll
            for (int p = 0; p < 4; ++p) {
                int m2 = tid + p * 256;
                int k = m2 >> 4, eq = m2 & 15;
                sU[k * 16 + SW(eq, k)] = Cg[m2];
            }
        }
        __syncthreads();   // B3: sctx ready

        // num-GEMM: 8 rows x 4 e, K=64 ; den folded in
        #pragma unroll 4
        for (int kb = 0; kb < 16; ++kb) {
            f32x4 a[8];
            #pragma unroll
            for (int j = 0; j < 8; ++j) {
                int row = rg * 8 + j;
                a[j] = qp[row * 16 + SW(kb, row)];
            }
            f32x4 ks = sks[f * 16 + kb];
            #pragma unroll
            for (int kk = 0; kk < 4; ++kk) {
                int k = kb * 4 + kk;
                f32x4 bq = sU[k * 16 + SW(cg, k)];
                #pragma unroll
                for (int j = 0; j < 8; ++j) num[j] += a[j][kk] * bq;
            }
            #pragma unroll
            for (int j = 0; j < 8; ++j)
                den[j] += a[j][0] * ks[0] + a[j][1] * ks[1]
                        + a[j][2] * ks[2] + a[j][3] * ks[3];
        }
        __syncthreads();   // B4: sU/qp reads done before next-f staging
    }

    #pragma unroll
    for (int j = 0; j < 8; ++j) {
        float dinv = 1.0f / den[j];
        *(f32x4*)(out + (rowbase + rg * 8 + j) * DH + cg * 4) = num[j] * dinv;
    }
}

extern "C" void kernel_launch(void* const* d_in, const int* in_sizes, int n_in,
                              void* d_out, int out_size, void* d_ws, size_t ws_size,
                              hipStream_t stream) {
    const f32* q    = (const f32*)d_in[0];
    const f32* k    = (const f32*)d_in[1];
    const f32* v    = (const f32*)d_in[2];
    const f32* proj = (const f32*)d_in[3];
    f32* out     = (f32*)d_out;
    f32* ctx_ws  = (f32*)d_ws;
    f32* ksum_ws = ctx_ws + CTX_FLOATS;

    hipLaunchKernelGGL(zero_ws_kernel, dim3(WS_FLOATS / 4 / 256), dim3(256), 0,
                       stream, (f32x4*)d_ws);
    hipLaunchKernelGGL(kside_kernel, dim3(BH * 8), dim3(256), 0, stream,
                       k, v, proj, ctx_ws, ksum_ws);
    hipLaunchKernelGGL(qside_kernel, dim3(BH * 32), dim3(256), 0, stream,
                       q, proj, ctx_ws, ksum_ws, out);
}